// Round 6
// baseline (645.246 us; speedup 1.0000x reference)
//
#include <hip/hip_runtime.h>

// ---------------------------------------------------------------------------
// GraphSAGE 2-layer (mean aggr) + linear classifier, fp32, N=100K, D=64, E=16N
// R5: linear layers = (node, feat-quarter) threads. quarter = tid>>6 is
//  wave-uniform so weight addresses stay scalar (s_load + v_fmac). 4x wave
//  count vs R4 (6.1 waves/SIMD) hides s_load / vmem latency that capped R4
//  at 22% VALUBusy with 1.5 waves/SIMD.
// ---------------------------------------------------------------------------

#define SCAN_BS 1024
#define SCATTER_PASSES 8

__global__ void zero_i32_kernel(int* __restrict__ p, int n) {
  int i = blockIdx.x * blockDim.x + threadIdx.x;
  if (i < n) p[i] = 0;
}

__global__ void hist_kernel(const int* __restrict__ dst, int* __restrict__ deg, int ne) {
  int e = blockIdx.x * blockDim.x + threadIdx.x;
  if (e < ne) atomicAdd(&deg[dst[e]], 1);
}

__device__ __forceinline__ int block_scan_inclusive_1024(int v, int* wsums) {
  int lane = threadIdx.x & 63;
  int wid = threadIdx.x >> 6;
  int s = v;
#pragma unroll
  for (int off = 1; off < 64; off <<= 1) {
    int t = __shfl_up(s, off);
    if (lane >= off) s += t;
  }
  if (lane == 63) wsums[wid] = s;
  __syncthreads();
  if (wid == 0) {
    int ws = (lane < 16) ? wsums[lane] : 0;
#pragma unroll
    for (int off = 1; off < 16; off <<= 1) {
      int t = __shfl_up(ws, off);
      if (lane >= off) ws += t;
    }
    if (lane < 16) wsums[lane] = ws;
  }
  __syncthreads();
  if (wid > 0) s += wsums[wid - 1];
  return s;
}

__global__ void __launch_bounds__(SCAN_BS) scan_a_kernel(const int* __restrict__ deg,
                                                         int* __restrict__ local_excl,
                                                         int* __restrict__ bsums, int n) {
  __shared__ int wsums[16];
  int i = blockIdx.x * SCAN_BS + threadIdx.x;
  int v = (i < n) ? deg[i] : 0;
  int inc = block_scan_inclusive_1024(v, wsums);
  if (i < n) local_excl[i] = inc - v;
  if (threadIdx.x == SCAN_BS - 1) bsums[blockIdx.x] = inc;
}

__global__ void __launch_bounds__(SCAN_BS) scan_b_kernel(const int* __restrict__ bsums,
                                                         int* __restrict__ boffs, int nb) {
  __shared__ int wsums[16];
  int v = ((int)threadIdx.x < nb) ? bsums[threadIdx.x] : 0;
  int inc = block_scan_inclusive_1024(v, wsums);
  if ((int)threadIdx.x < nb) boffs[threadIdx.x] = inc - v;
  if ((int)threadIdx.x == nb - 1) boffs[nb] = inc;
}

__global__ void scan_c_kernel(int* __restrict__ row_ptr, int* __restrict__ cursor,
                              const int* __restrict__ boffs, int n, int nb) {
  int i = blockIdx.x * blockDim.x + threadIdx.x;
  if (i < n) {
    int v = row_ptr[i] + boffs[i >> 10];
    row_ptr[i] = v;
    cursor[i] = v;
  }
  if (i == n) row_ptr[n] = boffs[nb];
}

__global__ void scatter_pass_kernel(const int* __restrict__ src, const int* __restrict__ dst,
                                    int* __restrict__ cursor, int* __restrict__ col,
                                    int ne, int lo, int hi) {
  int e = blockIdx.x * blockDim.x + threadIdx.x;
  if (e < ne) {
    int d = dst[e];
    if (d >= lo && d < hi) {
      int pos = atomicAdd(&cursor[d], 1);
      col[pos] = src[e];
    }
  }
}

// one wave per node, one feature per lane; scalarized col reads, 8 gathers in flight
__global__ void __launch_bounds__(256) aggregate_kernel(const float* __restrict__ xin,
                                                        const int* __restrict__ row_ptr,
                                                        const int* __restrict__ col,
                                                        float* __restrict__ outp, int n) {
  int gwave = (blockIdx.x * 256 + threadIdx.x) >> 6;
  int lane = threadIdx.x & 63;
  if (gwave >= n) return;
  int m = __builtin_amdgcn_readfirstlane(gwave);
  int start = row_ptr[m];
  int end = row_ptr[m + 1];
  float a0 = 0.f, a1 = 0.f, a2 = 0.f, a3 = 0.f, a4 = 0.f, a5 = 0.f, a6 = 0.f, a7 = 0.f;
  int e = start;
  for (; e + 8 <= end; e += 8) {
    int c0 = col[e + 0], c1 = col[e + 1], c2 = col[e + 2], c3 = col[e + 3];
    int c4 = col[e + 4], c5 = col[e + 5], c6 = col[e + 6], c7 = col[e + 7];
    a0 += xin[(size_t)c0 * 64 + lane];
    a1 += xin[(size_t)c1 * 64 + lane];
    a2 += xin[(size_t)c2 * 64 + lane];
    a3 += xin[(size_t)c3 * 64 + lane];
    a4 += xin[(size_t)c4 * 64 + lane];
    a5 += xin[(size_t)c5 * 64 + lane];
    a6 += xin[(size_t)c6 * 64 + lane];
    a7 += xin[(size_t)c7 * 64 + lane];
  }
  for (; e < end; ++e) a0 += xin[(size_t)col[e] * 64 + lane];
  float acc = ((a0 + a1) + (a2 + a3)) + ((a4 + a5) + (a6 + a7));
  int d = end - start;
  float inv = 1.0f / (float)((d > 0) ? d : 1);
  outp[(size_t)m * 64 + lane] = acc * inv;
}

// out = relu(agg @ Wl + b + xin @ Wr)
// thread = (node = blk*64 + lane, quarter = tid>>6). Weight addresses depend
// only on quarter + unroll constants -> wave-uniform -> s_load.
__global__ void __launch_bounds__(256) lin_relu_kernel(const float* __restrict__ agg,
                                                       const float* __restrict__ xin,
                                                       const float* __restrict__ Wl,
                                                       const float* __restrict__ bias,
                                                       const float* __restrict__ Wr,
                                                       float* __restrict__ outp, int n) {
  int q = threadIdx.x >> 6;          // wave-uniform
  int lane = threadIdx.x & 63;
  int node = blockIdx.x * 64 + lane;
  if (node >= n) return;
  const float4* ar = (const float4*)(agg + (size_t)node * 64);
  const float4* xr = (const float4*)(xin + (size_t)node * 64);
  const float* wl = Wl + q * 16;
  const float* wr = Wr + q * 16;
  float acc[16];
#pragma unroll
  for (int j = 0; j < 16; ++j) acc[j] = bias[q * 16 + j];  // uniform -> s_load
#pragma unroll
  for (int k4 = 0; k4 < 16; ++k4) {
    float4 av = ar[k4];
    float4 xv = xr[k4];
#pragma unroll
    for (int j = 0; j < 16; ++j) {
      acc[j] = fmaf(av.x, wl[(k4 * 4 + 0) * 64 + j], acc[j]);
      acc[j] = fmaf(av.y, wl[(k4 * 4 + 1) * 64 + j], acc[j]);
      acc[j] = fmaf(av.z, wl[(k4 * 4 + 2) * 64 + j], acc[j]);
      acc[j] = fmaf(av.w, wl[(k4 * 4 + 3) * 64 + j], acc[j]);
      acc[j] = fmaf(xv.x, wr[(k4 * 4 + 0) * 64 + j], acc[j]);
      acc[j] = fmaf(xv.y, wr[(k4 * 4 + 1) * 64 + j], acc[j]);
      acc[j] = fmaf(xv.z, wr[(k4 * 4 + 2) * 64 + j], acc[j]);
      acc[j] = fmaf(xv.w, wr[(k4 * 4 + 3) * 64 + j], acc[j]);
    }
  }
  float4* op = (float4*)(outp + (size_t)node * 64 + q * 16);
#pragma unroll
  for (int j4 = 0; j4 < 4; ++j4) {
    float4 v;
    v.x = fmaxf(acc[j4 * 4 + 0], 0.f);
    v.y = fmaxf(acc[j4 * 4 + 1], 0.f);
    v.z = fmaxf(acc[j4 * 4 + 2], 0.f);
    v.w = fmaxf(acc[j4 * 4 + 3], 0.f);
    op[j4] = v;
  }
}

// h2 = agg @ Wl + b + hin @ Wr; out = h2 @ Wc + bc -> [n, 2]
// same (node, quarter) partition; classifier partials reduced across the 4
// quarters (cross-wave) via 2 KB LDS.
__global__ void __launch_bounds__(256) lin2_cls_kernel(const float* __restrict__ agg,
                                                       const float* __restrict__ hin,
                                                       const float* __restrict__ Wl,
                                                       const float* __restrict__ bias,
                                                       const float* __restrict__ Wr,
                                                       const float* __restrict__ Wc,
                                                       const float* __restrict__ bc,
                                                       float* __restrict__ outp, int n) {
  __shared__ float red[4][64][2];
  int q = threadIdx.x >> 6;          // wave-uniform
  int lane = threadIdx.x & 63;
  int node = blockIdx.x * 64 + lane;
  bool valid = node < n;
  int mnode = valid ? node : (n - 1);  // safe address; result masked
  const float4* ar = (const float4*)(agg + (size_t)mnode * 64);
  const float4* xr = (const float4*)(hin + (size_t)mnode * 64);
  const float* wl = Wl + q * 16;
  const float* wr = Wr + q * 16;
  float acc[16];
#pragma unroll
  for (int j = 0; j < 16; ++j) acc[j] = bias[q * 16 + j];
#pragma unroll
  for (int k4 = 0; k4 < 16; ++k4) {
    float4 av = ar[k4];
    float4 xv = xr[k4];
#pragma unroll
    for (int j = 0; j < 16; ++j) {
      acc[j] = fmaf(av.x, wl[(k4 * 4 + 0) * 64 + j], acc[j]);
      acc[j] = fmaf(av.y, wl[(k4 * 4 + 1) * 64 + j], acc[j]);
      acc[j] = fmaf(av.z, wl[(k4 * 4 + 2) * 64 + j], acc[j]);
      acc[j] = fmaf(av.w, wl[(k4 * 4 + 3) * 64 + j], acc[j]);
      acc[j] = fmaf(xv.x, wr[(k4 * 4 + 0) * 64 + j], acc[j]);
      acc[j] = fmaf(xv.y, wr[(k4 * 4 + 1) * 64 + j], acc[j]);
      acc[j] = fmaf(xv.z, wr[(k4 * 4 + 2) * 64 + j], acc[j]);
      acc[j] = fmaf(xv.w, wr[(k4 * 4 + 3) * 64 + j], acc[j]);
    }
  }
  float p0 = 0.f, p1 = 0.f;
#pragma unroll
  for (int j = 0; j < 16; ++j) {
    p0 = fmaf(acc[j], Wc[(q * 16 + j) * 2 + 0], p0);  // uniform -> s_load
    p1 = fmaf(acc[j], Wc[(q * 16 + j) * 2 + 1], p1);
  }
  red[q][lane][0] = p0;
  red[q][lane][1] = p1;
  __syncthreads();
  if (q == 0 && valid) {
    float s0 = red[0][lane][0] + red[1][lane][0] + red[2][lane][0] + red[3][lane][0];
    float s1 = red[0][lane][1] + red[1][lane][1] + red[2][lane][1] + red[3][lane][1];
    float2 o;
    o.x = s0 + bc[0];
    o.y = s1 + bc[1];
    *(float2*)(outp + (size_t)node * 2) = o;
  }
}

extern "C" void kernel_launch(void* const* d_in, const int* in_sizes, int n_in,
                              void* d_out, int out_size, void* d_ws, size_t ws_size,
                              hipStream_t stream) {
  const float* x   = (const float*)d_in[0];
  const int*   ei  = (const int*)d_in[1];
  const float* W1l = (const float*)d_in[2];
  const float* b1  = (const float*)d_in[3];
  const float* W1r = (const float*)d_in[4];
  const float* W2l = (const float*)d_in[5];
  const float* b2  = (const float*)d_in[6];
  const float* W2r = (const float*)d_in[7];
  const float* Wc  = (const float*)d_in[8];
  const float* bc  = (const float*)d_in[9];
  float* out = (float*)d_out;

  const int n  = in_sizes[0] / 64;   // 100000
  const int ne = in_sizes[1] / 2;    // 1600000
  const int* src = ei;
  const int* dst = ei + ne;

  char* ws = (char*)d_ws;
  size_t off = 0;
  auto carve = [&](size_t bytes) -> void* {
    void* p = ws + off;
    off += (bytes + 255) & ~(size_t)255;
    return p;
  };
  const int nb = (n + SCAN_BS - 1) / SCAN_BS;  // 98
  int* deg     = (int*)carve((size_t)n * 4);
  int* row_ptr = (int*)carve((size_t)(n + 1) * 4);
  int* cursor  = (int*)carve((size_t)n * 4);
  int* bsums   = (int*)carve((size_t)(nb + 1) * 4);
  int* boffs   = (int*)carve((size_t)(nb + 1) * 4);
  int* col     = (int*)carve((size_t)ne * 4);
  float* agg   = (float*)carve((size_t)n * 64 * 4);
  float* h     = (float*)carve((size_t)n * 64 * 4);
  (void)ws_size;

  zero_i32_kernel<<<(n + 255) / 256, 256, 0, stream>>>(deg, n);
  hist_kernel<<<(ne + 255) / 256, 256, 0, stream>>>(dst, deg, ne);

  scan_a_kernel<<<nb, SCAN_BS, 0, stream>>>(deg, row_ptr, bsums, n);
  scan_b_kernel<<<1, SCAN_BS, 0, stream>>>(bsums, boffs, nb);
  scan_c_kernel<<<(n + 256) / 256, 256, 0, stream>>>(row_ptr, cursor, boffs, n, nb);

  {
    int W = (n + SCATTER_PASSES - 1) / SCATTER_PASSES;
    for (int p = 0; p < SCATTER_PASSES; ++p) {
      int lo = p * W;
      int hi = (lo + W < n) ? (lo + W) : n;
      scatter_pass_kernel<<<(ne + 255) / 256, 256, 0, stream>>>(src, dst, cursor, col, ne, lo, hi);
    }
  }

  aggregate_kernel<<<(n * 64 + 255) / 256, 256, 0, stream>>>(x, row_ptr, col, agg, n);
  lin_relu_kernel<<<(n + 63) / 64, 256, 0, stream>>>(agg, x, W1l, b1, W1r, h, n);

  aggregate_kernel<<<(n * 64 + 255) / 256, 256, 0, stream>>>(h, row_ptr, col, agg, n);
  lin2_cls_kernel<<<(n + 63) / 64, 256, 0, stream>>>(agg, h, W2l, b2, W2r, Wc, bc, out, n);
}

// Round 7
// 590.340 us; speedup vs baseline: 1.0930x; 1.0930x over previous
//
#include <hip/hip_runtime.h>

// ---------------------------------------------------------------------------
// GraphSAGE 2-layer (mean aggr) + linear classifier, fp32, N=100K, D=64, E=16N
// R6: linear layers stage the 64-node input tile in LDS (coalesced float4
//  global loads; [node][k] stride-65 -> 2-way=free bank aliasing), compute as
//  (node=lane, quarter=tid>>6) with wave-uniform weight s_loads. Fixes R5's
//  256B-stride uncoalesced vmem (64 lines/instr, 4x re-read).
//  Scatter: 4 dst-range passes (8 passes' L3 re-scans ate the write-amp win).
// ---------------------------------------------------------------------------

#define SCAN_BS 1024
#define SCATTER_PASSES 4

__global__ void zero_i32_kernel(int* __restrict__ p, int n) {
  int i = blockIdx.x * blockDim.x + threadIdx.x;
  if (i < n) p[i] = 0;
}

__global__ void hist_kernel(const int* __restrict__ dst, int* __restrict__ deg, int ne) {
  int e = blockIdx.x * blockDim.x + threadIdx.x;
  if (e < ne) atomicAdd(&deg[dst[e]], 1);
}

__device__ __forceinline__ int block_scan_inclusive_1024(int v, int* wsums) {
  int lane = threadIdx.x & 63;
  int wid = threadIdx.x >> 6;
  int s = v;
#pragma unroll
  for (int off = 1; off < 64; off <<= 1) {
    int t = __shfl_up(s, off);
    if (lane >= off) s += t;
  }
  if (lane == 63) wsums[wid] = s;
  __syncthreads();
  if (wid == 0) {
    int ws = (lane < 16) ? wsums[lane] : 0;
#pragma unroll
    for (int off = 1; off < 16; off <<= 1) {
      int t = __shfl_up(ws, off);
      if (lane >= off) ws += t;
    }
    if (lane < 16) wsums[lane] = ws;
  }
  __syncthreads();
  if (wid > 0) s += wsums[wid - 1];
  return s;
}

__global__ void __launch_bounds__(SCAN_BS) scan_a_kernel(const int* __restrict__ deg,
                                                         int* __restrict__ local_excl,
                                                         int* __restrict__ bsums, int n) {
  __shared__ int wsums[16];
  int i = blockIdx.x * SCAN_BS + threadIdx.x;
  int v = (i < n) ? deg[i] : 0;
  int inc = block_scan_inclusive_1024(v, wsums);
  if (i < n) local_excl[i] = inc - v;
  if (threadIdx.x == SCAN_BS - 1) bsums[blockIdx.x] = inc;
}

__global__ void __launch_bounds__(SCAN_BS) scan_b_kernel(const int* __restrict__ bsums,
                                                         int* __restrict__ boffs, int nb) {
  __shared__ int wsums[16];
  int v = ((int)threadIdx.x < nb) ? bsums[threadIdx.x] : 0;
  int inc = block_scan_inclusive_1024(v, wsums);
  if ((int)threadIdx.x < nb) boffs[threadIdx.x] = inc - v;
  if ((int)threadIdx.x == nb - 1) boffs[nb] = inc;
}

__global__ void scan_c_kernel(int* __restrict__ row_ptr, int* __restrict__ cursor,
                              const int* __restrict__ boffs, int n, int nb) {
  int i = blockIdx.x * blockDim.x + threadIdx.x;
  if (i < n) {
    int v = row_ptr[i] + boffs[i >> 10];
    row_ptr[i] = v;
    cursor[i] = v;
  }
  if (i == n) row_ptr[n] = boffs[nb];
}

__global__ void scatter_pass_kernel(const int* __restrict__ src, const int* __restrict__ dst,
                                    int* __restrict__ cursor, int* __restrict__ col,
                                    int ne, int lo, int hi) {
  int e = blockIdx.x * blockDim.x + threadIdx.x;
  if (e < ne) {
    int d = dst[e];
    if (d >= lo && d < hi) {
      int pos = atomicAdd(&cursor[d], 1);
      col[pos] = src[e];
    }
  }
}

// one wave per node, one feature per lane; scalarized col reads, 8 gathers in flight
__global__ void __launch_bounds__(256) aggregate_kernel(const float* __restrict__ xin,
                                                        const int* __restrict__ row_ptr,
                                                        const int* __restrict__ col,
                                                        float* __restrict__ outp, int n) {
  int gwave = (blockIdx.x * 256 + threadIdx.x) >> 6;
  int lane = threadIdx.x & 63;
  if (gwave >= n) return;
  int m = __builtin_amdgcn_readfirstlane(gwave);
  int start = row_ptr[m];
  int end = row_ptr[m + 1];
  float a0 = 0.f, a1 = 0.f, a2 = 0.f, a3 = 0.f, a4 = 0.f, a5 = 0.f, a6 = 0.f, a7 = 0.f;
  int e = start;
  for (; e + 8 <= end; e += 8) {
    int c0 = col[e + 0], c1 = col[e + 1], c2 = col[e + 2], c3 = col[e + 3];
    int c4 = col[e + 4], c5 = col[e + 5], c6 = col[e + 6], c7 = col[e + 7];
    a0 += xin[(size_t)c0 * 64 + lane];
    a1 += xin[(size_t)c1 * 64 + lane];
    a2 += xin[(size_t)c2 * 64 + lane];
    a3 += xin[(size_t)c3 * 64 + lane];
    a4 += xin[(size_t)c4 * 64 + lane];
    a5 += xin[(size_t)c5 * 64 + lane];
    a6 += xin[(size_t)c6 * 64 + lane];
    a7 += xin[(size_t)c7 * 64 + lane];
  }
  for (; e < end; ++e) a0 += xin[(size_t)col[e] * 64 + lane];
  float acc = ((a0 + a1) + (a2 + a3)) + ((a4 + a5) + (a6 + a7));
  int d = end - start;
  float inv = 1.0f / (float)((d > 0) ? d : 1);
  outp[(size_t)m * 64 + lane] = acc * inv;
}

// ---- linear layers: LDS-staged 64-node tile --------------------------------
// stage: coalesced float4 global loads -> sA/sX [node][k], row stride 65.
// compute: thread = (node = lane, quarter = tid>>6), weights wave-uniform.

__device__ __forceinline__ void stage_tile(const float* __restrict__ a_g,
                                           const float* __restrict__ x_g,
                                           float* __restrict__ sA, float* __restrict__ sX,
                                           int tile0, int nrows) {
  const float4* ag = (const float4*)(a_g + (size_t)tile0 * 64);
  const float4* xg = (const float4*)(x_g + (size_t)tile0 * 64);
  int nf4 = nrows * 16;
  for (int i = threadIdx.x; i < nf4; i += 256) {
    float4 a = ag[i];
    float4 xv = xg[i];
    int row = i >> 4;
    int c = (i & 15) * 4;
    float* pa = &sA[row * 65 + c];
    float* px = &sX[row * 65 + c];
    pa[0] = a.x; pa[1] = a.y; pa[2] = a.z; pa[3] = a.w;
    px[0] = xv.x; px[1] = xv.y; px[2] = xv.z; px[3] = xv.w;
  }
}

__global__ void __launch_bounds__(256) lin_relu_kernel(const float* __restrict__ agg,
                                                       const float* __restrict__ xin,
                                                       const float* __restrict__ Wl,
                                                       const float* __restrict__ bias,
                                                       const float* __restrict__ Wr,
                                                       float* __restrict__ outp, int n) {
  __shared__ float sA[64 * 65];
  __shared__ float sX[64 * 65];
  int tile0 = blockIdx.x * 64;
  int nrows = n - tile0;
  if (nrows > 64) nrows = 64;
  stage_tile(agg, xin, sA, sX, tile0, nrows);
  __syncthreads();
  int q = threadIdx.x >> 6;  // wave-uniform
  int lane = threadIdx.x & 63;
  int node = tile0 + lane;
  const float* sa = &sA[lane * 65];
  const float* sx = &sX[lane * 65];
  float acc[16];
#pragma unroll
  for (int j = 0; j < 16; ++j) acc[j] = bias[q * 16 + j];  // uniform -> s_load
#pragma unroll
  for (int k = 0; k < 64; ++k) {
    float a = sa[k];
    float xv = sx[k];
    const float* wlk = &Wl[k * 64 + q * 16];  // uniform -> s_load
    const float* wrk = &Wr[k * 64 + q * 16];
#pragma unroll
    for (int j = 0; j < 16; ++j) {
      acc[j] = fmaf(a, wlk[j], acc[j]);
      acc[j] = fmaf(xv, wrk[j], acc[j]);
    }
  }
  if (node < n) {
    float4* op = (float4*)(outp + (size_t)node * 64 + q * 16);
#pragma unroll
    for (int j4 = 0; j4 < 4; ++j4) {
      float4 v;
      v.x = fmaxf(acc[j4 * 4 + 0], 0.f);
      v.y = fmaxf(acc[j4 * 4 + 1], 0.f);
      v.z = fmaxf(acc[j4 * 4 + 2], 0.f);
      v.w = fmaxf(acc[j4 * 4 + 3], 0.f);
      op[j4] = v;
    }
  }
}

__global__ void __launch_bounds__(256) lin2_cls_kernel(const float* __restrict__ agg,
                                                       const float* __restrict__ hin,
                                                       const float* __restrict__ Wl,
                                                       const float* __restrict__ bias,
                                                       const float* __restrict__ Wr,
                                                       const float* __restrict__ Wc,
                                                       const float* __restrict__ bc,
                                                       float* __restrict__ outp, int n) {
  __shared__ float sA[64 * 65];
  __shared__ float sX[64 * 65];
  __shared__ float red[4][64][2];
  int tile0 = blockIdx.x * 64;
  int nrows = n - tile0;
  if (nrows > 64) nrows = 64;
  stage_tile(agg, hin, sA, sX, tile0, nrows);
  __syncthreads();
  int q = threadIdx.x >> 6;  // wave-uniform
  int lane = threadIdx.x & 63;
  int node = tile0 + lane;
  const float* sa = &sA[lane * 65];
  const float* sx = &sX[lane * 65];
  float acc[16];
#pragma unroll
  for (int j = 0; j < 16; ++j) acc[j] = bias[q * 16 + j];
#pragma unroll
  for (int k = 0; k < 64; ++k) {
    float a = sa[k];
    float xv = sx[k];
    const float* wlk = &Wl[k * 64 + q * 16];
    const float* wrk = &Wr[k * 64 + q * 16];
#pragma unroll
    for (int j = 0; j < 16; ++j) {
      acc[j] = fmaf(a, wlk[j], acc[j]);
      acc[j] = fmaf(xv, wrk[j], acc[j]);
    }
  }
  float p0 = 0.f, p1 = 0.f;
#pragma unroll
  for (int j = 0; j < 16; ++j) {
    p0 = fmaf(acc[j], Wc[(q * 16 + j) * 2 + 0], p0);  // uniform -> s_load
    p1 = fmaf(acc[j], Wc[(q * 16 + j) * 2 + 1], p1);
  }
  red[q][lane][0] = p0;
  red[q][lane][1] = p1;
  __syncthreads();
  if (q == 0 && node < n) {
    float s0 = red[0][lane][0] + red[1][lane][0] + red[2][lane][0] + red[3][lane][0];
    float s1 = red[0][lane][1] + red[1][lane][1] + red[2][lane][1] + red[3][lane][1];
    float2 o;
    o.x = s0 + bc[0];
    o.y = s1 + bc[1];
    *(float2*)(outp + (size_t)node * 2) = o;
  }
}

extern "C" void kernel_launch(void* const* d_in, const int* in_sizes, int n_in,
                              void* d_out, int out_size, void* d_ws, size_t ws_size,
                              hipStream_t stream) {
  const float* x   = (const float*)d_in[0];
  const int*   ei  = (const int*)d_in[1];
  const float* W1l = (const float*)d_in[2];
  const float* b1  = (const float*)d_in[3];
  const float* W1r = (const float*)d_in[4];
  const float* W2l = (const float*)d_in[5];
  const float* b2  = (const float*)d_in[6];
  const float* W2r = (const float*)d_in[7];
  const float* Wc  = (const float*)d_in[8];
  const float* bc  = (const float*)d_in[9];
  float* out = (float*)d_out;

  const int n  = in_sizes[0] / 64;   // 100000
  const int ne = in_sizes[1] / 2;    // 1600000
  const int* src = ei;
  const int* dst = ei + ne;

  char* ws = (char*)d_ws;
  size_t off = 0;
  auto carve = [&](size_t bytes) -> void* {
    void* p = ws + off;
    off += (bytes + 255) & ~(size_t)255;
    return p;
  };
  const int nb = (n + SCAN_BS - 1) / SCAN_BS;  // 98
  int* deg     = (int*)carve((size_t)n * 4);
  int* row_ptr = (int*)carve((size_t)(n + 1) * 4);
  int* cursor  = (int*)carve((size_t)n * 4);
  int* bsums   = (int*)carve((size_t)(nb + 1) * 4);
  int* boffs   = (int*)carve((size_t)(nb + 1) * 4);
  int* col     = (int*)carve((size_t)ne * 4);
  float* agg   = (float*)carve((size_t)n * 64 * 4);
  float* h     = (float*)carve((size_t)n * 64 * 4);
  (void)ws_size;

  zero_i32_kernel<<<(n + 255) / 256, 256, 0, stream>>>(deg, n);
  hist_kernel<<<(ne + 255) / 256, 256, 0, stream>>>(dst, deg, ne);

  scan_a_kernel<<<nb, SCAN_BS, 0, stream>>>(deg, row_ptr, bsums, n);
  scan_b_kernel<<<1, SCAN_BS, 0, stream>>>(bsums, boffs, nb);
  scan_c_kernel<<<(n + 256) / 256, 256, 0, stream>>>(row_ptr, cursor, boffs, n, nb);

  {
    int W = (n + SCATTER_PASSES - 1) / SCATTER_PASSES;
    for (int p = 0; p < SCATTER_PASSES; ++p) {
      int lo = p * W;
      int hi = (lo + W < n) ? (lo + W) : n;
      scatter_pass_kernel<<<(ne + 255) / 256, 256, 0, stream>>>(src, dst, cursor, col, ne, lo, hi);
    }
  }

  aggregate_kernel<<<(n * 64 + 255) / 256, 256, 0, stream>>>(x, row_ptr, col, agg, n);
  lin_relu_kernel<<<(n + 63) / 64, 256, 0, stream>>>(agg, x, W1l, b1, W1r, h, n);

  aggregate_kernel<<<(n * 64 + 255) / 256, 256, 0, stream>>>(h, row_ptr, col, agg, n);
  lin2_cls_kernel<<<(n + 63) / 64, 256, 0, stream>>>(agg, h, W2l, b2, W2r, Wc, bc, out, n);
}